// Round 7
// baseline (164.770 us; speedup 1.0000x reference)
//
#include <hip/hip_runtime.h>

// out[m][n][o] = sum_i x[m][n][i]*Weff_n[o][i] + b[o]
// Weff_n = W + gA·gB/16 + nA[n]·nB[n]/8  (folded per workgroup into LDS as bf16)
// M=B*T=384 rows, N=512 nodes, IN=OUT=256.
//
// Round 7: one 1024-thread block (16 waves) per node, 128 KB LDS Weff,
// 4 waves/SIMD pinned via amdgpu_waves_per_eu(4,4) (VGPR budget 128; r5's
// launch_bounds heuristic gave 64 -> spill). Register plan shrunk to ~95:
// waves 4(m) x 4(o); 3 passes x 2 register-blocked row-tiles; 8 MFMA/kt-step.

typedef __attribute__((ext_vector_type(4))) float f32x4;
typedef __attribute__((ext_vector_type(8))) short short8;

__device__ __forceinline__ unsigned short f2bf(float f) {
    unsigned int u = __builtin_bit_cast(unsigned int, f);
    u += 0x7fffu + ((u >> 16) & 1u);          // round-to-nearest-even
    return (unsigned short)(u >> 16);
}

__device__ __forceinline__ short8 cvt8(f32x4 a, f32x4 b) {
    short8 r;
    r[0] = (short)f2bf(a[0]); r[1] = (short)f2bf(a[1]);
    r[2] = (short)f2bf(a[2]); r[3] = (short)f2bf(a[3]);
    r[4] = (short)f2bf(b[0]); r[5] = (short)f2bf(b[1]);
    r[6] = (short)f2bf(b[2]); r[7] = (short)f2bf(b[3]);
    return r;
}

__global__ __launch_bounds__(1024)
__attribute__((amdgpu_waves_per_eu(4, 4)))
void fused_node_lora(
    const float* __restrict__ x, const float* __restrict__ W,
    const float* __restrict__ bias, const float* __restrict__ gA,
    const float* __restrict__ gB, const float* __restrict__ nA,
    const float* __restrict__ nB, float* __restrict__ out)
{
    extern __shared__ __align__(16) char smem[];   // Weff bf16 [256 o][256 i], XOR-swizzled, 128 KB
    const int node = blockIdx.x;
    const int tid  = threadIdx.x;
    const int lane = tid & 63;
    const int w    = tid >> 6;                     // wave 0..15
    const int l15  = lane & 15;
    const int kblk = lane >> 4;                    // 0..3

    // ---- early x prefetch (independent of LDS) so post-fold stream starts hot ----
    const int wm = w & 3;                          // m-group: 6 row-tiles (3 passes of 2)
    const int wo = w >> 2;                         // o-quarter: ot = wo*4 .. wo*4+3
    const long TSTR = 16L * 512 * 256;             // +16 m-rows in floats
    const float* xb = x + ((long)(wm * 96 + l15) * 512 + node) * 256 + kblk * 8;

    f32x4 buf[2][2][2];                            // [depth%2][tile j][half]
    // step s = pass*8 + kt, s in 0..23; tiles = wm*6 + pass*2 + j
    #define LDX(s2) do {                                                          \
        const int _p = (s2) >> 3, _k = (s2) & 7;                                  \
        _Pragma("unroll")                                                         \
        for (int _j = 0; _j < 2; ++_j) {                                          \
            const f32x4* _q = (const f32x4*)(xb + (long)(_p * 2 + _j) * TSTR + _k * 32); \
            buf[(s2) & 1][_j][0] = _q[0];                                         \
            buf[(s2) & 1][_j][1] = _q[1];                                         \
        } } while (0)

    LDX(0); LDX(1);

    // ---------------- fold phase: Weff into LDS via one K=32 MFMA step ----------------
    {
        // A' (IN x 32): k<16 -> gA[i][k]/16 ; 16<=k<24 -> nA[n][i][k-16]/8 ; k>=24 -> 0
        const int i = w * 16 + l15;                // each wave: one 16-row i-tile
        const float* ap = (kblk == 2) ? (nA + ((long)node * 256 + i) * 8)
                                      : (gA + (long)i * 16 + (kblk & 1) * 8);
        const float sc = (kblk == 2) ? 0.125f : ((kblk == 3) ? 0.0f : 0.0625f);
        const float4 q0 = *(const float4*)(ap);
        const float4 q1 = *(const float4*)(ap + 4);
        short8 afr;
        afr[0] = (short)f2bf(q0.x * sc); afr[1] = (short)f2bf(q0.y * sc);
        afr[2] = (short)f2bf(q0.z * sc); afr[3] = (short)f2bf(q0.w * sc);
        afr[4] = (short)f2bf(q1.x * sc); afr[5] = (short)f2bf(q1.y * sc);
        afr[6] = (short)f2bf(q1.z * sc); afr[7] = (short)f2bf(q1.w * sc);

        // B' (32 x OUT): k<16 -> gB[k][o] ; 16<=k<24 -> nB[n][k-16][o] ; k>=24 -> (don't care, A'=0)
        for (int ot = 0; ot < 16; ++ot) {
            const int o = ot * 16 + l15;
            const float* bp = (kblk == 0) ? (gB + o)
                             : (kblk == 1) ? (gB + 2048 + o)
                                           : (nB + (long)node * 2048 + o);
            short8 bfr;
            #pragma unroll
            for (int j = 0; j < 8; ++j) bfr[j] = (short)f2bf(bp[j * 256]);
            const f32x4 zero = {0.f, 0.f, 0.f, 0.f};
            f32x4 c = __builtin_amdgcn_mfma_f32_16x16x32_bf16(afr, bfr, zero, 0, 0, 0);
            const int ib = w * 16 + kblk * 4;      // 4 consecutive i per lane
            const float4 wv = *(const float4*)(W + (long)o * 256 + ib);
            unsigned int lo = (unsigned int)f2bf(wv.x + c[0]) |
                              ((unsigned int)f2bf(wv.y + c[1]) << 16);
            unsigned int hi = (unsigned int)f2bf(wv.z + c[2]) |
                              ((unsigned int)f2bf(wv.w + c[3]) << 16);
            int byte = (o << 9) + (ib << 1);
            byte ^= ((o & 7) << 4);                // swizzle (conflict-free r/w)
            *reinterpret_cast<uint2*>(smem + byte) = make_uint2(lo, hi);
        }
    }
    __syncthreads();

    // ---------------- main GEMM: x (global, 2-deep prefetch) x Weff (LDS) ----------------
    #pragma unroll
    for (int p = 0; p < 3; ++p) {
        f32x4 acc[2][4];
        #pragma unroll
        for (int j = 0; j < 2; ++j)
            #pragma unroll
            for (int oi = 0; oi < 4; ++oi) { const f32x4 z = {0.f,0.f,0.f,0.f}; acc[j][oi] = z; }

        #pragma unroll
        for (int kt = 0; kt < 8; ++kt) {
            const int s = p * 8 + kt;
            short8 af[2];
            #pragma unroll
            for (int j = 0; j < 2; ++j) af[j] = cvt8(buf[s & 1][j][0], buf[s & 1][j][1]);
            if (s + 2 < 24) LDX(s + 2);            // spans pass boundary: no cold start
            const unsigned int kaddr =
                ((((unsigned)l15 << 9) | ((unsigned)kt << 6) | ((unsigned)kblk << 4))
                 ^ (((unsigned)(l15 & 7)) << 4));
            #pragma unroll
            for (int oi = 0; oi < 4; ++oi) {
                const short8 bf = *reinterpret_cast<const short8*>(
                    smem + kaddr + (unsigned)(wo * 4 + oi) * 8192u);
                #pragma unroll
                for (int j = 0; j < 2; ++j)
                    acc[j][oi] = __builtin_amdgcn_mfma_f32_16x16x32_bf16(bf, af[j], acc[j][oi], 0, 0, 0);
            }
        }

        // epilogue: lane writes out[m][n][oc .. oc+3], m = tile*16 + l15
        #pragma unroll
        for (int oi = 0; oi < 4; ++oi) {
            const int oc = (wo * 4 + oi) * 16 + kblk * 4;
            const f32x4 bv = *(const f32x4*)(bias + oc);
            #pragma unroll
            for (int j = 0; j < 2; ++j) {
                f32x4 v = acc[j][oi];
                v[0] += bv[0]; v[1] += bv[1]; v[2] += bv[2]; v[3] += bv[3];
                float* ob = out + ((long)((wm * 6 + p * 2 + j) * 16 + l15) * 512 + node) * 256 + oc;
                __builtin_nontemporal_store(v, (f32x4*)ob);
            }
        }
    }
    #undef LDX
}

extern "C" void kernel_launch(void* const* d_in, const int* in_sizes, int n_in,
                              void* d_out, int out_size, void* d_ws, size_t ws_size,
                              hipStream_t stream) {
    const float* x  = (const float*)d_in[0];
    const float* W  = (const float*)d_in[1];
    const float* b  = (const float*)d_in[2];
    const float* gA = (const float*)d_in[3];
    const float* gB = (const float*)d_in[4];
    const float* nA = (const float*)d_in[5];
    const float* nB = (const float*)d_in[6];
    float* out = (float*)d_out;
    (void)hipFuncSetAttribute((const void*)fused_node_lora,
                              hipFuncAttributeMaxDynamicSharedMemorySize, 131072);
    fused_node_lora<<<dim3(512), dim3(1024), 131072, stream>>>(x, W, b, gA, gB, nA, nB, out);
}

// Round 8
// 130.045 us; speedup vs baseline: 1.2670x; 1.2670x over previous
//
#include <hip/hip_runtime.h>

// out[m][n][o] = sum_i x[m][n][i]*Weff_n[o][i] + b[o]
// Weff_n = W + gA·gB/16 + nA[n]·nB[n]/8
// M=B*T=384 rows, N=512 nodes, IN=OUT=256.
//
// Round 8: twin o-half blocks (64 KB LDS, 2 blocks/CU -> 4 waves/SIMD) with
// register demand genuinely <= budget: 2-tile register blocking, ~90 VGPR
// (buf 32 + acc 32 + af 8 + addr ~20). waves_per_eu(4) is satisfiable
// WITHOUT spill this time. Twins (node, half) = bid, bid+8 -> same XCD so
// the duplicated x read dedups in L2 (proven in r6: FETCH 107 MB).
// Waves: 4(m) x 2(o); 3 passes x 2 tiles; 8 MFMA / 4 LDS reads per kt-step.

typedef __attribute__((ext_vector_type(4))) float f32x4;
typedef __attribute__((ext_vector_type(8))) short short8;

__device__ __forceinline__ unsigned short f2bf(float f) {
    unsigned int u = __builtin_bit_cast(unsigned int, f);
    u += 0x7fffu + ((u >> 16) & 1u);          // round-to-nearest-even
    return (unsigned short)(u >> 16);
}

__device__ __forceinline__ short8 cvt8(f32x4 a, f32x4 b) {
    short8 r;
    r[0] = (short)f2bf(a[0]); r[1] = (short)f2bf(a[1]);
    r[2] = (short)f2bf(a[2]); r[3] = (short)f2bf(a[3]);
    r[4] = (short)f2bf(b[0]); r[5] = (short)f2bf(b[1]);
    r[6] = (short)f2bf(b[2]); r[7] = (short)f2bf(b[3]);
    return r;
}

__global__ __launch_bounds__(512, 1)
__attribute__((amdgpu_waves_per_eu(4, 8)))
void fused_node_lora(
    const float* __restrict__ x, const float* __restrict__ W,
    const float* __restrict__ bias, const float* __restrict__ gA,
    const float* __restrict__ gB, const float* __restrict__ nA,
    const float* __restrict__ nB, float* __restrict__ out)
{
    extern __shared__ __align__(16) char smem[];   // Weff bf16 slice [128 o][256 i], swizzled, 64 KB
    const int bid  = blockIdx.x;
    const int node = ((bid >> 4) << 3) | (bid & 7);   // twins (node, half 0/1) = bid, bid+8 -> same XCD
    const int half = (bid >> 3) & 1;
    const int tid  = threadIdx.x;
    const int lane = tid & 63;
    const int w    = tid >> 6;                     // wave 0..7
    const int l15  = lane & 15;
    const int kblk = lane >> 4;                    // 0..3

    // ---- early x prefetch (independent of LDS) so post-fold stream starts hot ----
    const int wm = w & 3;                          // m-group: 6 row-tiles (3 passes of 2)
    const int wo = w >> 2;                         // o-quarter within this half
    const long TSTR = 16L * 512 * 256;             // +16 m-rows in floats
    const float* xb = x + ((long)(wm * 96 + l15) * 512 + node) * 256 + kblk * 8;

    f32x4 buf[2][2][2];                            // [depth%2][tile j][half] = 32 VGPR
    // step s = pass*8 + kt, s in 0..23; row-tile = wm*6 + pass*2 + j
    #define LDX(s2) do {                                                          \
        const int _p = (s2) >> 3, _k = (s2) & 7;                                  \
        _Pragma("unroll")                                                         \
        for (int _j = 0; _j < 2; ++_j) {                                          \
            const f32x4* _q = (const f32x4*)(xb + (long)(_p * 2 + _j) * TSTR + _k * 32); \
            buf[(s2) & 1][_j][0] = _q[0];                                         \
            buf[(s2) & 1][_j][1] = _q[1];                                         \
        } } while (0)

    LDX(0); LDX(1);

    // ---------------- fold phase: Weff slice into LDS via one K=32 MFMA step ----------------
    {
        // A' (IN x 32): k<16 -> gA[i][k]/16 ; 16<=k<24 -> nA[n][i][k-16]/8 ; k>=24 -> 0
        short8 afr[2];
        #pragma unroll
        for (int t = 0; t < 2; ++t) {
            const int i = (w * 2 + t) * 16 + l15;
            const float* ap = (kblk == 2) ? (nA + ((long)node * 256 + i) * 8)
                                          : (gA + (long)i * 16 + (kblk & 1) * 8);
            const float sc = (kblk == 2) ? 0.125f : ((kblk == 3) ? 0.0f : 0.0625f);
            const float4 q0 = *(const float4*)(ap);
            const float4 q1 = *(const float4*)(ap + 4);
            short8 a;
            a[0] = (short)f2bf(q0.x * sc); a[1] = (short)f2bf(q0.y * sc);
            a[2] = (short)f2bf(q0.z * sc); a[3] = (short)f2bf(q0.w * sc);
            a[4] = (short)f2bf(q1.x * sc); a[5] = (short)f2bf(q1.y * sc);
            a[6] = (short)f2bf(q1.z * sc); a[7] = (short)f2bf(q1.w * sc);
            afr[t] = a;
        }
        // B' (32 x 128 o-slice): k<16 -> gB[k][o] ; 16<=k<24 -> nB[n][k-16][o]
        for (int ot = 0; ot < 8; ++ot) {
            const int ol = ot * 16 + l15;          // o_local within half
            const int o  = half * 128 + ol;        // global o
            const float* bp = (kblk == 0) ? (gB + o)
                             : (kblk == 1) ? (gB + 2048 + o)
                                           : (nB + (long)node * 2048 + o);
            short8 bfr;
            #pragma unroll
            for (int j = 0; j < 8; ++j) bfr[j] = (short)f2bf(bp[j * 256]);
            const f32x4 zero = {0.f, 0.f, 0.f, 0.f};
            f32x4 c0 = __builtin_amdgcn_mfma_f32_16x16x32_bf16(afr[0], bfr, zero, 0, 0, 0);
            f32x4 c1 = __builtin_amdgcn_mfma_f32_16x16x32_bf16(afr[1], bfr, zero, 0, 0, 0);
            #pragma unroll
            for (int t = 0; t < 2; ++t) {
                const f32x4 c = t ? c1 : c0;
                const int ib = (w * 2 + t) * 16 + kblk * 4;   // 4 consecutive i per lane
                const float4 wv = *(const float4*)(W + (long)o * 256 + ib);
                unsigned int lo = (unsigned int)f2bf(wv.x + c[0]) |
                                  ((unsigned int)f2bf(wv.y + c[1]) << 16);
                unsigned int hi = (unsigned int)f2bf(wv.z + c[2]) |
                                  ((unsigned int)f2bf(wv.w + c[3]) << 16);
                int byte = (ol << 9) + (ib << 1);
                byte ^= ((ol & 7) << 4);                       // swizzle (conflict-free r/w)
                *reinterpret_cast<uint2*>(smem + byte) = make_uint2(lo, hi);
            }
        }
    }
    __syncthreads();

    // ---------------- main GEMM: x (2-deep prefetch, L2-dedup w/ twin) x Weff-slice (LDS) ----------------
    #pragma unroll
    for (int p = 0; p < 3; ++p) {
        f32x4 acc[2][4];                           // 32 regs (mostly AGPR)
        #pragma unroll
        for (int j = 0; j < 2; ++j)
            #pragma unroll
            for (int oi = 0; oi < 4; ++oi) { const f32x4 z = {0.f,0.f,0.f,0.f}; acc[j][oi] = z; }

        #pragma unroll
        for (int kt = 0; kt < 8; ++kt) {
            const int s = p * 8 + kt;
            short8 af[2];
            #pragma unroll
            for (int j = 0; j < 2; ++j) af[j] = cvt8(buf[s & 1][j][0], buf[s & 1][j][1]);
            if (s + 2 < 24) LDX(s + 2);            // spans pass boundary: no cold start
            const unsigned int kaddr =
                ((((unsigned)l15 << 9) | ((unsigned)kt << 6) | ((unsigned)kblk << 4))
                 ^ (((unsigned)(l15 & 7)) << 4));
            #pragma unroll
            for (int oi = 0; oi < 4; ++oi) {
                const short8 bf = *reinterpret_cast<const short8*>(
                    smem + kaddr + (unsigned)(wo * 4 + oi) * 8192u);
                #pragma unroll
                for (int j = 0; j < 2; ++j)
                    acc[j][oi] = __builtin_amdgcn_mfma_f32_16x16x32_bf16(bf, af[j], acc[j][oi], 0, 0, 0);
            }
        }

        // epilogue: lane writes out[m][n][oc .. oc+3], m = tile*16 + l15
        #pragma unroll
        for (int oi = 0; oi < 4; ++oi) {
            const int oc = half * 128 + (wo * 4 + oi) * 16 + kblk * 4;
            const f32x4 bv = *(const f32x4*)(bias + oc);
            #pragma unroll
            for (int j = 0; j < 2; ++j) {
                f32x4 v = acc[j][oi];
                v[0] += bv[0]; v[1] += bv[1]; v[2] += bv[2]; v[3] += bv[3];
                float* ob = out + ((long)((wm * 6 + p * 2 + j) * 16 + l15) * 512 + node) * 256 + oc;
                __builtin_nontemporal_store(v, (f32x4*)ob);
            }
        }
    }
    #undef LDX
}

extern "C" void kernel_launch(void* const* d_in, const int* in_sizes, int n_in,
                              void* d_out, int out_size, void* d_ws, size_t ws_size,
                              hipStream_t stream) {
    const float* x  = (const float*)d_in[0];
    const float* W  = (const float*)d_in[1];
    const float* b  = (const float*)d_in[2];
    const float* gA = (const float*)d_in[3];
    const float* gB = (const float*)d_in[4];
    const float* nA = (const float*)d_in[5];
    const float* nB = (const float*)d_in[6];
    float* out = (float*)d_out;
    (void)hipFuncSetAttribute((const void*)fused_node_lora,
                              hipFuncAttributeMaxDynamicSharedMemorySize, 65536);
    fused_node_lora<<<dim3(1024), dim3(512), 65536, stream>>>(x, W, b, gA, gB, nA, nB, out);
}

// Round 9
// 108.517 us; speedup vs baseline: 1.5184x; 1.1984x over previous
//
#include <hip/hip_runtime.h>

// out[m][n][o] = sum_i x[m][n][i]*Weff_n[o][i] + b[o]
// Weff_n = W + gA·gB/16 + nA[n]·nB[n]/8  (folded per workgroup into LDS as bf16)
// M=B*T=384 rows, N=512 nodes, IN=OUT=256.
//
// Round 9: r3 structure (the only shape the allocator handles cleanly:
// 512 thr, launch_bounds(512,1), no occupancy attributes, 116 VGPR + acc in
// AGPR). Changes vs r3: (a) x-prefetch depth 3 -> 4 (uses the ~44 spare regs
// under the 256/wave 2-wave threshold), (b) all 4 initial prefetches issued
// BEFORE the fold so the post-fold stream starts with a full memory pipe.

typedef __attribute__((ext_vector_type(4))) float f32x4;
typedef __attribute__((ext_vector_type(8))) short short8;

__device__ __forceinline__ unsigned short f2bf(float f) {
    unsigned int u = __builtin_bit_cast(unsigned int, f);
    u += 0x7fffu + ((u >> 16) & 1u);          // round-to-nearest-even
    return (unsigned short)(u >> 16);
}

__device__ __forceinline__ short8 cvt8(f32x4 a, f32x4 b) {
    short8 r;
    r[0] = (short)f2bf(a[0]); r[1] = (short)f2bf(a[1]);
    r[2] = (short)f2bf(a[2]); r[3] = (short)f2bf(a[3]);
    r[4] = (short)f2bf(b[0]); r[5] = (short)f2bf(b[1]);
    r[6] = (short)f2bf(b[2]); r[7] = (short)f2bf(b[3]);
    return r;
}

__global__ __launch_bounds__(512, 1) void fused_node_lora(
    const float* __restrict__ x, const float* __restrict__ W,
    const float* __restrict__ bias, const float* __restrict__ gA,
    const float* __restrict__ gB, const float* __restrict__ nA,
    const float* __restrict__ nB, float* __restrict__ out)
{
    extern __shared__ __align__(16) char smem[];   // Weff bf16 [256 o][256 i], XOR-swizzled, 128 KB
    const int node = blockIdx.x;
    const int tid  = threadIdx.x;
    const int lane = tid & 63;
    const int w    = tid >> 6;                     // wave 0..7
    const int l15  = lane & 15;
    const int kblk = lane >> 4;                    // 0..3

    // ---- 4-deep x prefetch ring, first 4 issued BEFORE the fold ----
    const int wm = w & 3;                          // m-group: 6 row-tiles (2 passes of 3)
    const int wo = w >> 2;                         // o-half: ot = wo*8 .. wo*8+7
    const long TSTR = 16L * 512 * 256;             // +16 m-rows in floats
    const float* xb = x + ((long)(wm * 96 + l15) * 512 + node) * 256 + kblk * 8;

    f32x4 buf[4][3][2];                            // [depth&3][tile j][half] = 96 regs
    #define LDX(s2) do {                                                          \
        const int _p = (s2) >> 3, _k = (s2) & 7;                                  \
        _Pragma("unroll")                                                         \
        for (int _j = 0; _j < 3; ++_j) {                                          \
            const f32x4* _q = (const f32x4*)(xb + (long)(_p * 3 + _j) * TSTR + _k * 32); \
            buf[(s2) & 3][_j][0] = _q[0];                                         \
            buf[(s2) & 3][_j][1] = _q[1];                                         \
        } } while (0)

    LDX(0); LDX(1); LDX(2); LDX(3);

    // ---------------- fold phase: Weff into LDS via one K=32 MFMA step ----------------
    {
        // A' (IN x 32): k<16 -> gA[i][k]/16 ; 16<=k<24 -> nA[n][i][k-16]/8 ; k>=24 -> 0
        short8 afr[2];
        #pragma unroll
        for (int t = 0; t < 2; ++t) {
            const int i = (w * 2 + t) * 16 + l15;
            const float* ap = (kblk == 2) ? (nA + ((long)node * 256 + i) * 8)
                                          : (gA + (long)i * 16 + (kblk & 1) * 8);
            const float sc = (kblk == 2) ? 0.125f : ((kblk == 3) ? 0.0f : 0.0625f);
            const float4 q0 = *(const float4*)(ap);
            const float4 q1 = *(const float4*)(ap + 4);
            short8 a;
            a[0] = (short)f2bf(q0.x * sc); a[1] = (short)f2bf(q0.y * sc);
            a[2] = (short)f2bf(q0.z * sc); a[3] = (short)f2bf(q0.w * sc);
            a[4] = (short)f2bf(q1.x * sc); a[5] = (short)f2bf(q1.y * sc);
            a[6] = (short)f2bf(q1.z * sc); a[7] = (short)f2bf(q1.w * sc);
            afr[t] = a;
        }
        // B' (32 x OUT): k<16 -> gB[k][o] ; 16<=k<24 -> nB[n][k-16][o] ; k>=24 -> (don't care, A'=0)
        for (int ot = 0; ot < 16; ++ot) {
            const int o = ot * 16 + l15;
            const float* bp = (kblk == 0) ? (gB + o)
                             : (kblk == 1) ? (gB + 2048 + o)
                                           : (nB + (long)node * 2048 + o);
            short8 bfr;
            #pragma unroll
            for (int j = 0; j < 8; ++j) bfr[j] = (short)f2bf(bp[j * 256]);
            const f32x4 zero = {0.f, 0.f, 0.f, 0.f};
            f32x4 c0 = __builtin_amdgcn_mfma_f32_16x16x32_bf16(afr[0], bfr, zero, 0, 0, 0);
            f32x4 c1 = __builtin_amdgcn_mfma_f32_16x16x32_bf16(afr[1], bfr, zero, 0, 0, 0);
            #pragma unroll
            for (int t = 0; t < 2; ++t) {
                const f32x4 c = t ? c1 : c0;
                const int ib = (w * 2 + t) * 16 + kblk * 4;   // 4 consecutive i per lane
                const float4 wv = *(const float4*)(W + (long)o * 256 + ib);
                unsigned int lo = (unsigned int)f2bf(wv.x + c[0]) |
                                  ((unsigned int)f2bf(wv.y + c[1]) << 16);
                unsigned int hi = (unsigned int)f2bf(wv.z + c[2]) |
                                  ((unsigned int)f2bf(wv.w + c[3]) << 16);
                int byte = (o << 9) + (ib << 1);
                byte ^= ((o & 7) << 4);                        // swizzle (conflict-free r/w)
                *reinterpret_cast<uint2*>(smem + byte) = make_uint2(lo, hi);
            }
        }
    }
    __syncthreads();

    // ---------------- main GEMM: x (global, 4-deep prefetch) x Weff (LDS) ----------------
    #pragma unroll
    for (int p = 0; p < 2; ++p) {
        f32x4 acc[3][8];
        #pragma unroll
        for (int j = 0; j < 3; ++j)
            #pragma unroll
            for (int oi = 0; oi < 8; ++oi) { const f32x4 z = {0.f,0.f,0.f,0.f}; acc[j][oi] = z; }

        #pragma unroll
        for (int kt = 0; kt < 8; ++kt) {
            const int s = p * 8 + kt;
            short8 af[3];
            #pragma unroll
            for (int j = 0; j < 3; ++j) af[j] = cvt8(buf[s & 3][j][0], buf[s & 3][j][1]);
            if (s + 4 < 16) LDX(s + 4);            // 4-deep, spans pass boundary
            const unsigned int kaddr =
                ((((unsigned)l15 << 9) | ((unsigned)kt << 6) | ((unsigned)kblk << 4))
                 ^ (((unsigned)(l15 & 7)) << 4));
            #pragma unroll
            for (int oi = 0; oi < 8; ++oi) {
                const short8 bf = *reinterpret_cast<const short8*>(
                    smem + kaddr + (unsigned)(wo * 8 + oi) * 8192u);
                #pragma unroll
                for (int j = 0; j < 3; ++j)
                    acc[j][oi] = __builtin_amdgcn_mfma_f32_16x16x32_bf16(bf, af[j], acc[j][oi], 0, 0, 0);
            }
        }

        // epilogue: lane writes out[m][n][oc .. oc+3], m = tile*16 + l15
        #pragma unroll
        for (int oi = 0; oi < 8; ++oi) {
            const int ot = wo * 8 + oi;
            const f32x4 bv = *(const f32x4*)(bias + ot * 16 + kblk * 4);
            #pragma unroll
            for (int j = 0; j < 3; ++j) {
                f32x4 v = acc[j][oi];
                v[0] += bv[0]; v[1] += bv[1]; v[2] += bv[2]; v[3] += bv[3];
                float* ob = out + ((long)((wm * 6 + p * 3 + j) * 16 + l15) * 512 + node) * 256
                            + ot * 16 + kblk * 4;
                __builtin_nontemporal_store(v, (f32x4*)ob);
            }
        }
    }
    #undef LDX
}

extern "C" void kernel_launch(void* const* d_in, const int* in_sizes, int n_in,
                              void* d_out, int out_size, void* d_ws, size_t ws_size,
                              hipStream_t stream) {
    const float* x  = (const float*)d_in[0];
    const float* W  = (const float*)d_in[1];
    const float* b  = (const float*)d_in[2];
    const float* gA = (const float*)d_in[3];
    const float* gB = (const float*)d_in[4];
    const float* nA = (const float*)d_in[5];
    const float* nB = (const float*)d_in[6];
    float* out = (float*)d_out;
    (void)hipFuncSetAttribute((const void*)fused_node_lora,
                              hipFuncAttributeMaxDynamicSharedMemorySize, 131072);
    fused_node_lora<<<dim3(512), dim3(512), 131072, stream>>>(x, W, b, gA, gB, nA, nB, out);
}